// Round 10
// baseline (143.792 us; speedup 1.0000x reference)
//
#include <hip/hip_runtime.h>

// MultiKeyframeProcessor — linear keyframe interpolation.
// latents:       [K=5, B=1, C=128, H=32, W=32] f32   (2.6 MB total)
// strengths:     [K=5] f32
// frame_indices: [K=5] i32 (sorted, unique, < 257)
// out: conditioning_latents [1,128,257,32,32] f32 (134.7 MB)
//      ++ conditioning_masks [1,257] f32
//
// Round-9 (rerun): R8 structure (register-resident keyframes, contiguous
// per-wave stores) with DOUBLED OCCUPANCY: grid=512 (2 blocks/CU, 2
// waves/SIMD) so store issue continues while one wave runs its per-t VALU
// weight block. R8 ran 1 wave/SIMD. Mandatory traffic: 2.6 MB read +
// 134.7 MB write => ~21 us floor @ 6.5 TB/s.

#define T_FRAMES 257
#define KK 5
#define PER_KEY 131072      // 1*128*32*32
#define HW 1024             // 32*32
#define LAT_OUT 33685504    // 128*257*1024

typedef float f32x4 __attribute__((ext_vector_type(4)));

__global__ __launch_bounds__(256) void mkp_kernel(
    const float* __restrict__ lat,
    const float* __restrict__ str,
    const int* __restrict__ fi,
    float* __restrict__ out)
{
    const int b    = blockIdx.x;        // [0, 512)
    const int tid  = threadIdx.x;       // [0, 256)
    const int c    = b & 127;           // channel
    const int seg  = b >> 7;            // t quarter (0..3)
    const int w    = tid >> 6;          // wave in block
    const int lane = tid & 63;

    // Keyframe tables: uniform scalar loads, K=5.
    int   fiv[KK];
    float sv[KK];
#pragma unroll
    for (int k = 0; k < KK; ++k) { fiv[k] = fi[k]; sv[k] = str[k]; }

    // Register-resident keyframe plane: lane l holds quarter-plane q's
    // f32x4 at float offset q*256 + l*4, for all 5 keyframes (80 VGPR).
    f32x4 kf[KK][4];
#pragma unroll
    for (int k = 0; k < KK; ++k) {
        const f32x4* src = (const f32x4*)(lat + k * PER_KEY + c * HW);
#pragma unroll
        for (int q = 0; q < 4; ++q)
            kf[k][q] = src[q * 64 + lane];
    }

    // This wave's contiguous t-range: segment seg covers [seg*64, seg*64+64)
    // (+1 tail plane for seg 3); wave w takes 16 planes (17 for last wave of
    // seg 3).
    const int t0 = seg * 64 + w * 16;
    const int t1 = (seg == 3 && w == 3) ? 257 : t0 + 16;

    float* po = out + c * (T_FRAMES * HW);   // channel base

    for (int t = t0; t < t1; ++t) {
        // searchsorted + weights (wave-uniform math, cheap).
        int j = -1;
#pragma unroll
        for (int k = 0; k < KK; ++k) j += (fiv[k] <= t) ? 1 : 0;
        const int j0 = (j < 0) ? 0 : j;
        const int j1 = (j + 1 > KK - 1) ? KK - 1 : j + 1;

        const bool before   = t < fiv[0];
        const bool after    = t > fiv[KK - 1];
        const bool at_kf    = (fiv[j0] == t);
        const bool interior = !(before || after || at_kf);

        const float tf    = (float)t;
        const float fj0   = (float)fiv[j0];
        const float fj1   = (float)fiv[j1];
        const float denom = fmaxf(fj1 - fj0, 1.0f);
        const float alpha = (tf - fj0) / denom;
        const float w1    = interior ? alpha : 0.0f;
        const float w0    = 1.0f - w1;

        // 5-wide weight vector, compile-time indexed (no scratch).
        float wk[KK];
#pragma unroll
        for (int k = 0; k < KK; ++k)
            wk[k] = ((k == j0) ? w0 : 0.0f) + ((k == j1) ? w1 : 0.0f);

        f32x4* plane4 = (f32x4*)(po + t * HW);
#pragma unroll
        for (int q = 0; q < 4; ++q) {
            f32x4 r = kf[0][q] * wk[0];
#pragma unroll
            for (int k = 1; k < KK; ++k) {
                r.x = fmaf(kf[k][q].x, wk[k], r.x);
                r.y = fmaf(kf[k][q].y, wk[k], r.y);
                r.z = fmaf(kf[k][q].z, wk[k], r.z);
                r.w = fmaf(kf[k][q].w, wk[k], r.w);
            }
            plane4[q * 64 + lane] = r;
        }
    }

    // conditioning_masks: c==0 blocks; segment seg covers its own t-range.
    const int nmask = (seg == 3) ? 65 : 64;
    if (c == 0 && tid < nmask) {
        const int t = seg * 64 + tid;
        int j = -1;
#pragma unroll
        for (int k = 0; k < KK; ++k) j += (fiv[k] <= t) ? 1 : 0;
        const int j0 = (j < 0) ? 0 : j;
        const int j1 = (j + 1 > KK - 1) ? KK - 1 : j + 1;

        const bool before   = t < fiv[0];
        const bool after    = t > fiv[KK - 1];
        const bool at_kf    = (fiv[j0] == t);
        const bool interior = !(before || after || at_kf);

        const float tf    = (float)t;
        const float fj0   = (float)fiv[j0];
        const float fj1   = (float)fiv[j1];
        const float denom = fmaxf(fj1 - fj0, 1.0f);
        const float alpha = (tf - fj0) / denom;
        const float w1    = interior ? alpha : 0.0f;
        const float w0    = 1.0f - w1;

        float m;
        if (before) {
            const float f0f = (float)fiv[0];
            m = sv[0] * fmaxf(1.0f - (f0f - tf) / fmaxf(f0f, 1.0f), 0.0f);
        } else if (after) {
            const float fLf = (float)fiv[KK - 1];
            m = sv[KK - 1] * fmaxf(1.0f - (tf - fLf) / ((float)T_FRAMES - fLf), 0.0f);
        } else {
            m = w0 * sv[j0] + w1 * sv[j1];
        }
        out[LAT_OUT + t] = m;
    }
}

extern "C" void kernel_launch(void* const* d_in, const int* in_sizes, int n_in,
                              void* d_out, int out_size, void* d_ws, size_t ws_size,
                              hipStream_t stream)
{
    const float* lat = (const float*)d_in[0];
    const float* str = (const float*)d_in[1];
    const int*   fi  = (const int*)d_in[2];
    float* out = (float*)d_out;

    const int grid = 512;   // (t-quarter, channel): 2 blocks/CU, 2 waves/SIMD
    mkp_kernel<<<grid, 256, 0, stream>>>(lat, str, fi, out);
}